// Round 1
// baseline (1439.589 us; speedup 1.0000x reference)
//
#include <hip/hip_runtime.h>
#include <hip/hip_bf16.h>

#define B_  32
#define L1_ 2048
#define L2_ 2048
#define D1_ 1024
#define D2_ 1024

typedef __attribute__((ext_vector_type(8))) short bf16x8;
typedef __attribute__((ext_vector_type(4))) float f32x4;

// ---------- helpers ----------
__device__ __forceinline__ unsigned enc_f(float x) {
  unsigned u = __float_as_uint(x);
  return (u & 0x80000000u) ? ~u : (u | 0x80000000u);
}
__device__ __forceinline__ float dec_f(unsigned e) {
  unsigned u = (e & 0x80000000u) ? (e ^ 0x80000000u) : ~e;
  return __uint_as_float(u);
}
// round-to-nearest-even bf16, returned as float bits with low 16 zeroed
__device__ __forceinline__ unsigned bf16_rne_bits(float x) {
  unsigned u = __float_as_uint(x);
  return (u + 0x7FFFu + ((u >> 16) & 1u)) & 0xFFFF0000u;
}
// pack hi (low 16) and lo (high 16) bf16 of x into one u32
__device__ __forceinline__ unsigned pack_hl(float x) {
  unsigned hb = bf16_rne_bits(x);
  float lo = x - __uint_as_float(hb);
  unsigned lb = bf16_rne_bits(lo);
  return (hb >> 16) | lb;
}
__device__ __forceinline__ void split_hl(float x, unsigned& h, unsigned& l) {
  unsigned hb = bf16_rne_bits(x);
  h = hb >> 16;
  float lo = x - __uint_as_float(hb);
  l = bf16_rne_bits(lo) >> 16;
}

// ---------- staging: 128 rows x 32 k-cols into LDS (stride 40 ushorts) ----------
__device__ __forceinline__ void stage_f32(const float* __restrict__ src, int k0,
                                          ushort* sh, ushort* sl, int tid) {
#pragma unroll
  for (int q = 0; q < 4; ++q) {
    int idx = q * 256 + tid;
    int row = idx >> 3;
    int c4  = (idx & 7) * 4;
    float4 v = *(const float4*)(src + (size_t)row * 1024 + k0 + c4);
    unsigned h0,h1,h2,h3,l0,l1,l2,l3;
    split_hl(v.x,h0,l0); split_hl(v.y,h1,l1); split_hl(v.z,h2,l2); split_hl(v.w,h3,l3);
    uint2 hw, lw;
    hw.x = h0 | (h1 << 16); hw.y = h2 | (h3 << 16);
    lw.x = l0 | (l1 << 16); lw.y = l2 | (l3 << 16);
    *(uint2*)&sh[row * 40 + c4] = hw;
    *(uint2*)&sl[row * 40 + c4] = lw;
  }
}
__device__ __forceinline__ void stage_pk(const unsigned* __restrict__ src, int k0,
                                         ushort* sh, ushort* sl, int tid) {
#pragma unroll
  for (int q = 0; q < 4; ++q) {
    int idx = q * 256 + tid;
    int row = idx >> 3;
    int c4  = (idx & 7) * 4;
    uint4 p = *(const uint4*)(src + (size_t)row * 1024 + k0 + c4);
    uint2 hw, lw;
    hw.x = (p.x & 0xFFFFu) | ((p.y & 0xFFFFu) << 16);
    hw.y = (p.z & 0xFFFFu) | ((p.w & 0xFFFFu) << 16);
    lw.x = (p.x >> 16) | (p.y & 0xFFFF0000u);
    lw.y = (p.z >> 16) | (p.w & 0xFFFF0000u);
    *(uint2*)&sh[row * 40 + c4] = hw;
    *(uint2*)&sl[row * 40 + c4] = lw;
  }
}

// ---------- transpose + decompose U: UTp[e][d] = pack(U[d][e]) ----------
__global__ void transdec_k(const float* __restrict__ U, unsigned* __restrict__ UTp) {
  __shared__ float t[32][33];
  const int tx = threadIdx.x, ty = threadIdx.y;
  const int e0 = blockIdx.x * 32, d0 = blockIdx.y * 32;
#pragma unroll
  for (int r = 0; r < 4; ++r)
    t[ty + r * 8][tx] = U[(size_t)(d0 + ty + r * 8) * D2_ + e0 + tx];
  __syncthreads();
#pragma unroll
  for (int r = 0; r < 4; ++r) {
    int e = ty + r * 8;
    UTp[(size_t)(e0 + e) * D1_ + d0 + tx] = pack_hl(t[tx][e]);
  }
}

// ---------- GEMM1: Y[z] = x1[z] @ U  (A fp32, B=UT packed) -> packed Y ----------
__global__ __launch_bounds__(256, 2) void gemm1_k(const float* __restrict__ x1g,
                                                  const unsigned* __restrict__ UTp,
                                                  unsigned* __restrict__ Yp) {
  __shared__ ushort sAh[128 * 40], sAl[128 * 40], sBh[128 * 40], sBl[128 * 40];
  const int tid = threadIdx.x;
  const int z = blockIdx.z;
  const int i0 = blockIdx.x * 128;
  const int e0 = blockIdx.y * 128;
  const float* A = x1g + (size_t)z * L1_ * D1_ + (size_t)i0 * D1_;
  const unsigned* Bp = UTp + (size_t)e0 * D1_;
  const int lane = tid & 63;
  const int wv = tid >> 6;
  const int wr = (wv >> 1) * 64, wc = (wv & 1) * 64;
  const int ln = lane & 15, kq = lane >> 4;
  const int koff = kq * 8;

  f32x4 acc[4][4];
#pragma unroll
  for (int m = 0; m < 4; ++m)
#pragma unroll
    for (int n = 0; n < 4; ++n) acc[m][n] = (f32x4){0.f, 0.f, 0.f, 0.f};

  for (int kt = 0; kt < 32; ++kt) {
    const int k0 = kt * 32;
    if (kt) __syncthreads();
    stage_f32(A, k0, sAh, sAl, tid);
    stage_pk(Bp, k0, sBh, sBl, tid);
    __syncthreads();
    bf16x8 ah[4], al[4], bh[4], bl[4];
#pragma unroll
    for (int m = 0; m < 4; ++m) {
      int r = wr + m * 16 + ln;
      ah[m] = *(const bf16x8*)&sAh[r * 40 + koff];
      al[m] = *(const bf16x8*)&sAl[r * 40 + koff];
    }
#pragma unroll
    for (int n = 0; n < 4; ++n) {
      int r = wc + n * 16 + ln;
      bh[n] = *(const bf16x8*)&sBh[r * 40 + koff];
      bl[n] = *(const bf16x8*)&sBl[r * 40 + koff];
    }
#pragma unroll
    for (int m = 0; m < 4; ++m)
#pragma unroll
      for (int n = 0; n < 4; ++n) {
        acc[m][n] = __builtin_amdgcn_mfma_f32_16x16x32_bf16(ah[m], bh[n], acc[m][n], 0, 0, 0);
        acc[m][n] = __builtin_amdgcn_mfma_f32_16x16x32_bf16(ah[m], bl[n], acc[m][n], 0, 0, 0);
        acc[m][n] = __builtin_amdgcn_mfma_f32_16x16x32_bf16(al[m], bh[n], acc[m][n], 0, 0, 0);
      }
  }
  unsigned* Y = Yp + (size_t)z * L1_ * D2_;
#pragma unroll
  for (int m = 0; m < 4; ++m) {
    int row = i0 + wr + m * 16 + kq * 4;
#pragma unroll
    for (int n = 0; n < 4; ++n) {
      int col = e0 + wc + n * 16 + ln;
#pragma unroll
      for (int r2 = 0; r2 < 4; ++r2)
        Y[(size_t)(row + r2) * D2_ + col] = pack_hl(acc[m][n][r2]);
    }
  }
}

// ---------- GEMM2: M[z] = Y[z] @ x2[z]^T, fused row/col max reduction ----------
__global__ __launch_bounds__(256, 2) void gemm2_k(const unsigned* __restrict__ Yp,
                                                  const float* __restrict__ x2g,
                                                  unsigned* __restrict__ rmxg,
                                                  unsigned* __restrict__ cmxg) {
  __shared__ ushort sAh[128 * 40], sAl[128 * 40], sBh[128 * 40], sBl[128 * 40];
  const int tid = threadIdx.x;
  const int z = blockIdx.z;
  const int i0 = blockIdx.x * 128;
  const int j0 = blockIdx.y * 128;
  const unsigned* A = Yp + (size_t)z * L1_ * D2_ + (size_t)i0 * D2_;
  const float* Bf = x2g + (size_t)z * L2_ * D2_ + (size_t)j0 * D2_;
  const int lane = tid & 63;
  const int wv = tid >> 6;
  const int wr = (wv >> 1) * 64, wc = (wv & 1) * 64;
  const int ln = lane & 15, kq = lane >> 4;
  const int koff = kq * 8;

  f32x4 acc[4][4];
#pragma unroll
  for (int m = 0; m < 4; ++m)
#pragma unroll
    for (int n = 0; n < 4; ++n) acc[m][n] = (f32x4){0.f, 0.f, 0.f, 0.f};

  for (int kt = 0; kt < 32; ++kt) {
    const int k0 = kt * 32;
    if (kt) __syncthreads();
    stage_pk(A, k0, sAh, sAl, tid);
    stage_f32(Bf, k0, sBh, sBl, tid);
    __syncthreads();
    bf16x8 ah[4], al[4], bh[4], bl[4];
#pragma unroll
    for (int m = 0; m < 4; ++m) {
      int r = wr + m * 16 + ln;
      ah[m] = *(const bf16x8*)&sAh[r * 40 + koff];
      al[m] = *(const bf16x8*)&sAl[r * 40 + koff];
    }
#pragma unroll
    for (int n = 0; n < 4; ++n) {
      int r = wc + n * 16 + ln;
      bh[n] = *(const bf16x8*)&sBh[r * 40 + koff];
      bl[n] = *(const bf16x8*)&sBl[r * 40 + koff];
    }
#pragma unroll
    for (int m = 0; m < 4; ++m)
#pragma unroll
      for (int n = 0; n < 4; ++n) {
        acc[m][n] = __builtin_amdgcn_mfma_f32_16x16x32_bf16(ah[m], bh[n], acc[m][n], 0, 0, 0);
        acc[m][n] = __builtin_amdgcn_mfma_f32_16x16x32_bf16(ah[m], bl[n], acc[m][n], 0, 0, 0);
        acc[m][n] = __builtin_amdgcn_mfma_f32_16x16x32_bf16(al[m], bh[n], acc[m][n], 0, 0, 0);
      }
  }

  // epilogue: tile row/col max -> global atomic max (encoded uint)
  __syncthreads();
  unsigned* rmx = (unsigned*)sAh;
  unsigned* cmx = rmx + 128;
  if (tid < 128) rmx[tid] = 0u;
  else if (tid < 256) cmx[tid - 128] = 0u;
  __syncthreads();

#pragma unroll
  for (int m = 0; m < 4; ++m) {
#pragma unroll
    for (int r2 = 0; r2 < 4; ++r2) {
      float v = acc[m][0][r2];
      v = fmaxf(v, acc[m][1][r2]);
      v = fmaxf(v, acc[m][2][r2]);
      v = fmaxf(v, acc[m][3][r2]);
#pragma unroll
      for (int s = 1; s < 16; s <<= 1) v = fmaxf(v, __shfl_xor(v, s));
      if (ln == 0) atomicMax(&rmx[wr + m * 16 + kq * 4 + r2], enc_f(v));
    }
  }
#pragma unroll
  for (int n = 0; n < 4; ++n) {
    float v = -3.4e38f;
#pragma unroll
    for (int m = 0; m < 4; ++m)
#pragma unroll
      for (int r2 = 0; r2 < 4; ++r2) v = fmaxf(v, acc[m][n][r2]);
#pragma unroll
    for (int s = 16; s < 64; s <<= 1) v = fmaxf(v, __shfl_xor(v, s));
    if (kq == 0) atomicMax(&cmx[wc + n * 16 + ln], enc_f(v));
  }
  __syncthreads();
  if (tid < 128) atomicMax(&rmxg[(size_t)z * L1_ + i0 + tid], rmx[tid]);
  else if (tid < 256) atomicMax(&cmxg[(size_t)z * L2_ + j0 + (tid - 128)], cmx[tid - 128]);
}

// ---------- softmax over 2048 encoded maxima per batch ----------
__global__ void softmax_k(const unsigned* __restrict__ enc, float* __restrict__ w) {
  __shared__ float red[256];
  const int b = blockIdx.x, tid = threadIdx.x;
  const unsigned* e = enc + (size_t)b * 2048;
  float* wb = w + (size_t)b * 2048;
  float vals[8];
  float lmax = -3.4e38f;
#pragma unroll
  for (int q = 0; q < 8; ++q) {
    float f = dec_f(e[q * 256 + tid]);
    vals[q] = f;
    lmax = fmaxf(lmax, f);
  }
  red[tid] = lmax; __syncthreads();
  for (int s = 128; s > 0; s >>= 1) {
    if (tid < s) red[tid] = fmaxf(red[tid], red[tid + s]);
    __syncthreads();
  }
  const float mx = red[0];
  __syncthreads();
  float lsum = 0.f;
#pragma unroll
  for (int q = 0; q < 8; ++q) { vals[q] = expf(vals[q] - mx); lsum += vals[q]; }
  red[tid] = lsum; __syncthreads();
  for (int s = 128; s > 0; s >>= 1) {
    if (tid < s) red[tid] += red[tid + s];
    __syncthreads();
  }
  const float inv = 1.f / red[0];
#pragma unroll
  for (int q = 0; q < 8; ++q) wb[q * 256 + tid] = vals[q] * inv;
}

// ---------- weighted sum: out[b,:] += sum_i w[b,i] * x[b,i,:] ----------
__global__ void wsum_k(const float* __restrict__ w, const float* __restrict__ x,
                       float* __restrict__ out) {
  __shared__ float ws[256];
  const int tid = threadIdx.x;
  const int b = blockIdx.y;
  const int i0 = blockIdx.x * 256;
  ws[tid] = w[(size_t)b * 2048 + i0 + tid];
  __syncthreads();
  const int d0 = tid * 4;
  const float* xb = x + ((size_t)b * 2048 + i0) * 1024 + d0;
  float4 acc = {0.f, 0.f, 0.f, 0.f};
  for (int i = 0; i < 256; ++i) {
    float4 v = *(const float4*)(xb + (size_t)i * 1024);
    float wi = ws[i];
    acc.x = fmaf(wi, v.x, acc.x);
    acc.y = fmaf(wi, v.y, acc.y);
    acc.z = fmaf(wi, v.z, acc.z);
    acc.w = fmaf(wi, v.w, acc.w);
  }
  float* o = out + (size_t)b * 1024 + d0;
  atomicAdd(o + 0, acc.x);
  atomicAdd(o + 1, acc.y);
  atomicAdd(o + 2, acc.z);
  atomicAdd(o + 3, acc.w);
}

extern "C" void kernel_launch(void* const* d_in, const int* in_sizes, int n_in,
                              void* d_out, int out_size, void* d_ws, size_t ws_size,
                              hipStream_t stream) {
  (void)in_sizes; (void)n_in; (void)out_size;
  const float* x1 = (const float*)d_in[0];
  const float* x2 = (const float*)d_in[1];
  const float* U  = (const float*)d_in[2];
  float* out = (float*)d_out;

  // workspace layout
  unsigned* UTp    = (unsigned*)d_ws;                 // D2*D1 u32  (4 MB)
  unsigned* rowmax = UTp + (size_t)D1_ * D2_;         // B*L1 u32
  unsigned* colmax = rowmax + (size_t)B_ * L1_;       // B*L2 u32
  float*    w1     = (float*)(colmax + (size_t)B_ * L2_);
  float*    w2     = w1 + (size_t)B_ * L1_;
  unsigned* Yp     = (unsigned*)(w2 + (size_t)B_ * L2_);
  size_t fixedBytes = (size_t)((char*)Yp - (char*)d_ws);
  size_t perY = (size_t)L1_ * D2_ * 4;
  int G = 1;
  if (ws_size > fixedBytes) {
    size_t g = (ws_size - fixedBytes) / perY;
    G = (g < 1) ? 1 : (g > (size_t)B_ ? B_ : (int)g);
  }

  hipMemsetAsync(d_out, 0, (size_t)2 * B_ * 1024 * 4, stream);
  hipMemsetAsync(rowmax, 0, (size_t)B_ * (L1_ + L2_) * 4, stream);

  transdec_k<<<dim3(32, 32), dim3(32, 8), 0, stream>>>(U, UTp);

  for (int g0 = 0; g0 < B_; g0 += G) {
    int Gc = (B_ - g0) < G ? (B_ - g0) : G;
    gemm1_k<<<dim3(16, 8, Gc), 256, 0, stream>>>(
        x1 + (size_t)g0 * L1_ * D1_, UTp, Yp);
    gemm2_k<<<dim3(16, 16, Gc), 256, 0, stream>>>(
        Yp, x2 + (size_t)g0 * L2_ * D2_,
        rowmax + (size_t)g0 * L1_, colmax + (size_t)g0 * L2_);
  }

  softmax_k<<<dim3(B_), 256, 0, stream>>>(rowmax, w1);
  softmax_k<<<dim3(B_), 256, 0, stream>>>(colmax, w2);

  wsum_k<<<dim3(8, B_), 256, 0, stream>>>(w1, x1, out);
  wsum_k<<<dim3(8, B_), 256, 0, stream>>>(w2, x2, out + (size_t)B_ * D1_);
}